// Round 23
// baseline (265.484 us; speedup 1.0000x reference)
//
#include <hip/hip_runtime.h>
#include <hip/hip_bf16.h>
#include <stdint.h>

#define T_DIM 4096
#define K_DIM 4096
#define N_DIM 11008

// ws layout (bytes): xq int8[T*K] | xs f32[T] | w8 int8[N*K]
#define XQ_OFF 0
#define XS_OFF 16777216
#define W8_OFF 16793600

typedef __attribute__((ext_vector_type(4))) int v4i;

// ---------------------------------------------------------------------------
// Kernel 1: FUSED quant + pack (grid-split, r21/r22-verified).
// ---------------------------------------------------------------------------
__global__ __launch_bounds__(256) void prep_kernel(
    const float* __restrict__ x, int8_t* __restrict__ xq, float* __restrict__ xs,
    const int* __restrict__ w32, int8_t* __restrict__ w8)
{
    if (blockIdx.x < T_DIM / 4) {
        const int wid   = threadIdx.x >> 6;
        const int lane  = threadIdx.x & 63;
        const int token = blockIdx.x * 4 + wid;

        const float* xrow = x + (size_t)token * K_DIM;

        float4 v[16];
        float am = 0.0f;
#pragma unroll
        for (int j = 0; j < 16; ++j) {
            v[j] = *(const float4*)(xrow + (size_t)(j * 64 + lane) * 4);
            am = fmaxf(am, fmaxf(fmaxf(fabsf(v[j].x), fabsf(v[j].y)),
                                 fmaxf(fabsf(v[j].z), fabsf(v[j].w))));
        }
#pragma unroll
        for (int m = 1; m < 64; m <<= 1)
            am = fmaxf(am, __shfl_xor(am, m, 64));

        const float scale = fmaxf(am, 1e-5f) / 127.0f;
        if (lane == 0) xs[token] = scale;

        uint32_t* qrow = (uint32_t*)(xq + (size_t)token * K_DIM);
#pragma unroll
        for (int j = 0; j < 16; ++j) {
            int q0 = min(127, max(-127, (int)rintf(v[j].x / scale)));
            int q1 = min(127, max(-127, (int)rintf(v[j].y / scale)));
            int q2 = min(127, max(-127, (int)rintf(v[j].z / scale)));
            int q3 = min(127, max(-127, (int)rintf(v[j].w / scale)));
            qrow[j * 64 + lane] = ((uint32_t)(uint8_t)(int8_t)q0)       |
                                  ((uint32_t)(uint8_t)(int8_t)q1 << 8)  |
                                  ((uint32_t)(uint8_t)(int8_t)q2 << 16) |
                                  ((uint32_t)(uint8_t)(int8_t)q3 << 24);
        }
    } else {
        const size_t tid = (size_t)(blockIdx.x - T_DIM / 4) * 256 + threadIdx.x;
        const int4* src = (const int4*)w32 + tid * 4;
        uint32_t o[4];
#pragma unroll
        for (int i = 0; i < 4; ++i) {
            int4 a = src[i];
            o[i] = ((uint32_t)a.x & 0xFFu) | (((uint32_t)a.y & 0xFFu) << 8) |
                   (((uint32_t)a.z & 0xFFu) << 16) | ((uint32_t)a.w << 24);
        }
        *(uint4*)(w8 + tid * 16) = make_uint4(o[0], o[1], o[2], o[3]);
    }
}

// ---------------------------------------------------------------------------
// Kernel 2: int8 MFMA GEMM — 256x256, 8 waves, single barrier per K-tile,
// DISTANCE-3 prefetch via 4-buffer LDS rotation (128KB): staging gets ~2 full
// tiles to land before its vmcnt. Race-free: stage target (t+3)%4 = (t-1)%4,
// consumed at t-1, done before end-of-(t-1) barrier. Wait ladder: vmcnt(8)
// steady / 4 / 0 drain. Swizzle/offsets/epilogue verbatim r18-r22 (refcheck'd).
// ---------------------------------------------------------------------------
#define BM 256
#define BN 256
#define BKB 64
#define NT (K_DIM / BKB)     // 64
#define BUF_SZ 16384         // 256 rows x 64 B

__global__ __launch_bounds__(512, 2) void gemm_i8_kernel(
    const int8_t* __restrict__ xq, const int8_t* __restrict__ w8,
    const float* __restrict__ xs, const float* __restrict__ wsc,
    const __hip_bfloat16* __restrict__ bias, float* __restrict__ out)
{
    __shared__ int8_t lds[4 * 2 * BUF_SZ];   // 128 KiB

    constexpr int NBN = N_DIM / BN;              // 43
    constexpr int NWG = (T_DIM / BM) * NBN;      // 688 (div by 8)
    constexpr int CPX = NWG / 8;                 // 86

    const int bid = blockIdx.x;
    const int b2  = (bid % 8) * CPX + bid / 8;   // bijective XCD swizzle
    const int bm  = b2 / NBN;
    const int bn  = b2 % NBN;

    const int tid  = threadIdx.x;
    const int wid  = tid >> 6;
    const int lane = tid & 63;
    const int wm   = wid >> 2;    // 0..1 (M)
    const int wn   = wid & 3;     // 0..3 (N)

    // fragment LDS byte offsets (chunk-XOR swizzled read side)
    const int fr = lane & 15, kg = lane >> 4;
    int offA[8], offB[4];
#pragma unroll
    for (int mi = 0; mi < 8; ++mi) {
        const int row = wm * 128 + mi * 16 + fr;
        offA[mi] = row * 64 + ((kg ^ ((row >> 1) & 3)) << 4);
    }
#pragma unroll
    for (int ni = 0; ni < 4; ++ni) {
        const int row = wn * 64 + ni * 16 + fr;
        offB[ni] = row * 64 + ((kg ^ ((row >> 1) & 3)) << 4);
    }

    // staging addressing (pre-swizzled source)
    const int srow  = tid >> 2;
    const int sslot = tid & 3;
    const int r0 = srow, r1 = 128 + srow;
    const int c0 = sslot ^ ((r0 >> 1) & 3);
    const int c1 = sslot ^ ((r1 >> 1) & 3);
    const int8_t* gA0 = xq + (size_t)(bm * BM + r0) * K_DIM + c0 * 16;
    const int8_t* gA1 = xq + (size_t)(bm * BM + r1) * K_DIM + c1 * 16;
    const int8_t* gB0 = w8 + (size_t)(bn * BM + r0) * K_DIM + c0 * 16;
    const int8_t* gB1 = w8 + (size_t)(bn * BM + r1) * K_DIM + c1 * 16;
    const int ldsW = wid * 1024;

    v4i acc[8][4];
#pragma unroll
    for (int mi = 0; mi < 8; ++mi)
#pragma unroll
        for (int ni = 0; ni < 4; ++ni) acc[mi][ni] = (v4i){0, 0, 0, 0};

#define STAGE(bufb, mat, Rr, kt)                                                \
    __builtin_amdgcn_global_load_lds(                                           \
        (const __attribute__((address_space(1))) void*)(                        \
            ((mat) ? ((Rr) ? gB1 : gB0) : ((Rr) ? gA1 : gA0)) +                 \
            (size_t)(kt) * BKB),                                                \
        (__attribute__((address_space(3))) void*)(                              \
            lds + ((bufb) * 2 + (mat)) * BUF_SZ + (Rr) * 8192 + ldsW),          \
        16, 0, 0)

#define STAGE_TILE(bufb, kt)                                                    \
    do {                                                                        \
        STAGE(bufb, 0, 0, kt); STAGE(bufb, 0, 1, kt);                           \
        STAGE(bufb, 1, 0, kt); STAGE(bufb, 1, 1, kt);                           \
    } while (0)

    // prologue: tiles 0,1,2 -> bufs 0,1,2 (12 loads/thread)
    STAGE_TILE(0, 0);
    STAGE_TILE(1, 1);
    STAGE_TILE(2, 2);
    asm volatile("s_waitcnt vmcnt(8)" ::: "memory");   // tile 0 landed
    __builtin_amdgcn_s_barrier();
    asm volatile("" ::: "memory");

    for (int t = 0; t < NT; ++t) {
        const int b  = t & 3;
        const int pb = (t + 3) & 3;    // == (t-1)&3: consumed at t-1, safe
        const int8_t* bA = lds + (b * 2 + 0) * BUF_SZ;
        const int8_t* bB = lds + (b * 2 + 1) * BUF_SZ;

        // issue tile t+3 staging first (earliest in flight)
        if (t + 3 < NT) STAGE_TILE(pb, t + 3);

        // read all fragments; compiler interleaves with MFMA via lgkmcnt
        v4i bF[4], aF[8];
#pragma unroll
        for (int ni = 0; ni < 4; ++ni) bF[ni] = *(const v4i*)(bB + offB[ni]);
#pragma unroll
        for (int mi = 0; mi < 8; ++mi) aF[mi] = *(const v4i*)(bA + offA[mi]);

        __builtin_amdgcn_s_setprio(1);
#pragma unroll
        for (int mi = 0; mi < 8; ++mi)
#pragma unroll
            for (int ni = 0; ni < 4; ++ni)
                acc[mi][ni] = __builtin_amdgcn_mfma_i32_16x16x64_i8(
                    aF[mi], bF[ni], acc[mi][ni], 0, 0, 0);
        __builtin_amdgcn_s_setprio(0);

        // wait: tile t+1's 4 loads complete (allow t+2, t+3 in flight)
        if (t < NT - 3)      asm volatile("s_waitcnt vmcnt(8)" ::: "memory");
        else if (t == NT - 3) asm volatile("s_waitcnt vmcnt(4)" ::: "memory");
        else                 asm volatile("s_waitcnt vmcnt(0)" ::: "memory");
        __builtin_amdgcn_s_barrier();
        asm volatile("" ::: "memory");
    }

    // epilogue (r17-r22-verified mapping; bf16-exact values in f32 slots)
    const int row0 = bm * BM + wm * 128 + (lane >> 4) * 4;
    const int col0 = bn * BN + wn * 64 + (lane & 15);
#pragma unroll
    for (int mi = 0; mi < 8; ++mi) {
#pragma unroll
        for (int j = 0; j < 4; ++j) {
            const int row = row0 + mi * 16 + j;
            const float xscale = xs[row];
#pragma unroll
            for (int ni = 0; ni < 4; ++ni) {
                const int col = col0 + ni * 16;
                float p_  = (float)acc[mi][ni][j] * xscale * wsc[col];
                float pb_ = __bfloat162float(__float2bfloat16(p_));
                float vb  = __bfloat162float(__float2bfloat16(
                                pb_ + __bfloat162float(bias[col])));
                out[(size_t)row * N_DIM + col] = vb;
            }
        }
    }
#undef STAGE
#undef STAGE_TILE
}

// ---------------------------------------------------------------------------
extern "C" void kernel_launch(void* const* d_in, const int* in_sizes, int n_in,
                              void* d_out, int out_size, void* d_ws, size_t ws_size,
                              hipStream_t stream)
{
    const float*          x    = (const float*)d_in[0];
    const int*            w32  = (const int*)d_in[1];
    const float*          wsc  = (const float*)d_in[2];
    const __hip_bfloat16* bias = (const __hip_bfloat16*)d_in[3];
    float*                out  = (float*)d_out;

    int8_t* xq = (int8_t*)d_ws + XQ_OFF;
    float*  xs = (float*)((char*)d_ws + XS_OFF);
    int8_t* w8 = (int8_t*)d_ws + W8_OFF;

    prep_kernel<<<T_DIM / 4 + (N_DIM * (K_DIM / 16)) / 256, 256, 0, stream>>>(
        x, xq, xs, w32, w8);
    gemm_i8_kernel<<<(T_DIM / BM) * (N_DIM / BN), 512, 0, stream>>>(
        xq, w8, xs, wsc, bias, out);
}

// Round 24
// 258.000 us; speedup vs baseline: 1.0290x; 1.0290x over previous
//
#include <hip/hip_runtime.h>
#include <hip/hip_bf16.h>
#include <stdint.h>

#define T_DIM 4096
#define K_DIM 4096
#define N_DIM 11008

// ws layout (bytes): xq int8[T*K] | xs f32[T] | w8 int8[N*K]
#define XQ_OFF 0
#define XS_OFF 16777216
#define W8_OFF 16793600

typedef __attribute__((ext_vector_type(4))) int v4i;

// ---------------------------------------------------------------------------
// Kernel 1: FUSED quant + pack (grid-split, r21-r23-verified).
// ---------------------------------------------------------------------------
__global__ __launch_bounds__(256) void prep_kernel(
    const float* __restrict__ x, int8_t* __restrict__ xq, float* __restrict__ xs,
    const int* __restrict__ w32, int8_t* __restrict__ w8)
{
    if (blockIdx.x < T_DIM / 4) {
        const int wid   = threadIdx.x >> 6;
        const int lane  = threadIdx.x & 63;
        const int token = blockIdx.x * 4 + wid;

        const float* xrow = x + (size_t)token * K_DIM;

        float4 v[16];
        float am = 0.0f;
#pragma unroll
        for (int j = 0; j < 16; ++j) {
            v[j] = *(const float4*)(xrow + (size_t)(j * 64 + lane) * 4);
            am = fmaxf(am, fmaxf(fmaxf(fabsf(v[j].x), fabsf(v[j].y)),
                                 fmaxf(fabsf(v[j].z), fabsf(v[j].w))));
        }
#pragma unroll
        for (int m = 1; m < 64; m <<= 1)
            am = fmaxf(am, __shfl_xor(am, m, 64));

        const float scale = fmaxf(am, 1e-5f) / 127.0f;
        if (lane == 0) xs[token] = scale;

        uint32_t* qrow = (uint32_t*)(xq + (size_t)token * K_DIM);
#pragma unroll
        for (int j = 0; j < 16; ++j) {
            int q0 = min(127, max(-127, (int)rintf(v[j].x / scale)));
            int q1 = min(127, max(-127, (int)rintf(v[j].y / scale)));
            int q2 = min(127, max(-127, (int)rintf(v[j].z / scale)));
            int q3 = min(127, max(-127, (int)rintf(v[j].w / scale)));
            qrow[j * 64 + lane] = ((uint32_t)(uint8_t)(int8_t)q0)       |
                                  ((uint32_t)(uint8_t)(int8_t)q1 << 8)  |
                                  ((uint32_t)(uint8_t)(int8_t)q2 << 16) |
                                  ((uint32_t)(uint8_t)(int8_t)q3 << 24);
        }
    } else {
        const size_t tid = (size_t)(blockIdx.x - T_DIM / 4) * 256 + threadIdx.x;
        const int4* src = (const int4*)w32 + tid * 4;
        uint32_t o[4];
#pragma unroll
        for (int i = 0; i < 4; ++i) {
            int4 a = src[i];
            o[i] = ((uint32_t)a.x & 0xFFu) | (((uint32_t)a.y & 0xFFu) << 8) |
                   (((uint32_t)a.z & 0xFFu) << 16) | ((uint32_t)a.w << 24);
        }
        *(uint4*)(w8 + tid * 16) = make_uint4(o[0], o[1], o[2], o[3]);
    }
}

// ---------------------------------------------------------------------------
// Kernel 2: int8 MFMA GEMM — 256x256 tile, BK=128 BYTES (64 MFMA per wave per
// barrier: 2x per-tile work to amortize per-tile fixed costs). 2-buffer
// distance-1 prefetch, 128KB LDS, 1 block/CU. Swizzle for 128B rows:
// chunk' = (ks*4+kg) ^ (row&7) -> 2-way (free). Staging pre-swizzle
// c = sslot ^ (srow&7) (round-invariant). Epilogue mapping = r17-r23 verbatim.
// ---------------------------------------------------------------------------
#define BM 256
#define BN 256
#define BKB 128
#define NT (K_DIM / BKB)     // 32
#define MAT_SZ 32768         // 256 rows x 128 B

__global__ __launch_bounds__(512, 2) void gemm_i8_kernel(
    const int8_t* __restrict__ xq, const int8_t* __restrict__ w8,
    const float* __restrict__ xs, const float* __restrict__ wsc,
    const __hip_bfloat16* __restrict__ bias, float* __restrict__ out)
{
    __shared__ int8_t lds[2 * 2 * MAT_SZ];   // 128 KiB: [buf][A/B][256*128]

    constexpr int NBN = N_DIM / BN;              // 43
    constexpr int NWG = (T_DIM / BM) * NBN;      // 688 (div by 8)
    constexpr int CPX = NWG / 8;                 // 86

    const int bid = blockIdx.x;
    const int b2  = (bid % 8) * CPX + bid / 8;   // bijective XCD swizzle
    const int bm  = b2 / NBN;
    const int bn  = b2 % NBN;

    const int tid  = threadIdx.x;
    const int wid  = tid >> 6;
    const int lane = tid & 63;
    const int wm   = wid >> 2;    // 0..1 (M)
    const int wn   = wid & 3;     // 0..3 (N)

    // fragment LDS byte offsets: row*128 + (((ks*4+kg) ^ (row&7)) * 16)
    const int fr = lane & 15, kg = lane >> 4;
    int offA[8][2], offB[4][2];
#pragma unroll
    for (int mi = 0; mi < 8; ++mi) {
        const int row = wm * 128 + mi * 16 + fr;
#pragma unroll
        for (int ks = 0; ks < 2; ++ks)
            offA[mi][ks] = row * 128 + (((ks * 4 + kg) ^ (row & 7)) << 4);
    }
#pragma unroll
    for (int ni = 0; ni < 4; ++ni) {
        const int row = wn * 64 + ni * 16 + fr;
#pragma unroll
        for (int ks = 0; ks < 2; ++ks)
            offB[ni][ks] = row * 128 + (((ks * 4 + kg) ^ (row & 7)) << 4);
    }

    // staging: 4 rounds x 64 rows; thread -> (srow = tid>>3, sslot = tid&7)
    // row = r*64 + srow; row&7 == srow&7 -> source chunk c = sslot ^ (srow&7)
    const int srow  = tid >> 3;
    const int sslot = tid & 7;
    const int csw   = (sslot ^ (srow & 7)) * 16;
    const int8_t* gA = xq + (size_t)(bm * BM + srow) * K_DIM + csw;
    const int8_t* gB = w8 + (size_t)(bn * BN + srow) * K_DIM + csw;
    const int ldsT = (tid & 511) * 16 - (lane * 16);   // wave-uniform part
    const int ldsBase = (tid >> 6) * 1024;             // == wid*1024
    (void)ldsT;

    v4i acc[8][4];
#pragma unroll
    for (int mi = 0; mi < 8; ++mi)
#pragma unroll
        for (int ni = 0; ni < 4; ++ni) acc[mi][ni] = (v4i){0, 0, 0, 0};

    // mat: 0=A, 1=B; r: staging round 0..3 (64 rows each)
#define STAGE(bufb, mat, r, kt)                                                 \
    __builtin_amdgcn_global_load_lds(                                           \
        (const __attribute__((address_space(1))) void*)(                        \
            ((mat) ? gB : gA) + (size_t)(r) * 64 * K_DIM + (size_t)(kt) * BKB), \
        (__attribute__((address_space(3))) void*)(                              \
            lds + ((bufb) * 2 + (mat)) * MAT_SZ + (r) * 8192 + ldsBase),        \
        16, 0, 0)

#define STAGE_TILE(bufb, kt)                                                    \
    do {                                                                        \
        STAGE(bufb, 0, 0, kt); STAGE(bufb, 0, 1, kt);                           \
        STAGE(bufb, 0, 2, kt); STAGE(bufb, 0, 3, kt);                           \
        STAGE(bufb, 1, 0, kt); STAGE(bufb, 1, 1, kt);                           \
        STAGE(bufb, 1, 2, kt); STAGE(bufb, 1, 3, kt);                           \
    } while (0)

    // prologue: tile 0 -> buf 0
    STAGE_TILE(0, 0);
    asm volatile("s_waitcnt vmcnt(0)" ::: "memory");
    __builtin_amdgcn_s_barrier();
    asm volatile("" ::: "memory");

    for (int t = 0; t < NT; ++t) {
        const int b  = t & 1;
        const int pn = b ^ 1;   // consumed at t-1 (readers done pre-barrier)
        const int8_t* bA = lds + (b * 2 + 0) * MAT_SZ;
        const int8_t* bB = lds + (b * 2 + 1) * MAT_SZ;

        if (t + 1 < NT) STAGE_TILE(pn, t + 1);   // 8 loads in flight over tile body

#pragma unroll
        for (int ks = 0; ks < 2; ++ks) {
            v4i bF[4], aF[8];
#pragma unroll
            for (int ni = 0; ni < 4; ++ni)
                bF[ni] = *(const v4i*)(bB + offB[ni][ks]);
#pragma unroll
            for (int mi = 0; mi < 8; ++mi)
                aF[mi] = *(const v4i*)(bA + offA[mi][ks]);

            __builtin_amdgcn_s_setprio(1);
#pragma unroll
            for (int mi = 0; mi < 8; ++mi)
#pragma unroll
                for (int ni = 0; ni < 4; ++ni)
                    acc[mi][ni] = __builtin_amdgcn_mfma_i32_16x16x64_i8(
                        aF[mi], bF[ni], acc[mi][ni], 0, 0, 0);
            __builtin_amdgcn_s_setprio(0);
        }

        asm volatile("s_waitcnt vmcnt(0)" ::: "memory");   // t+1 landed
        __builtin_amdgcn_s_barrier();
        asm volatile("" ::: "memory");
    }

    // epilogue (r17-r23-verified mapping; bf16-exact values in f32 slots)
    const int row0 = bm * BM + wm * 128 + (lane >> 4) * 4;
    const int col0 = bn * BN + wn * 64 + (lane & 15);
#pragma unroll
    for (int mi = 0; mi < 8; ++mi) {
#pragma unroll
        for (int j = 0; j < 4; ++j) {
            const int row = row0 + mi * 16 + j;
            const float xscale = xs[row];
#pragma unroll
            for (int ni = 0; ni < 4; ++ni) {
                const int col = col0 + ni * 16;
                float p_  = (float)acc[mi][ni][j] * xscale * wsc[col];
                float pb_ = __bfloat162float(__float2bfloat16(p_));
                float vb  = __bfloat162float(__float2bfloat16(
                                pb_ + __bfloat162float(bias[col])));
                out[(size_t)row * N_DIM + col] = vb;
            }
        }
    }
#undef STAGE
#undef STAGE_TILE
}

// ---------------------------------------------------------------------------
extern "C" void kernel_launch(void* const* d_in, const int* in_sizes, int n_in,
                              void* d_out, int out_size, void* d_ws, size_t ws_size,
                              hipStream_t stream)
{
    const float*          x    = (const float*)d_in[0];
    const int*            w32  = (const int*)d_in[1];
    const float*          wsc  = (const float*)d_in[2];
    const __hip_bfloat16* bias = (const __hip_bfloat16*)d_in[3];
    float*                out  = (float*)d_out;

    int8_t* xq = (int8_t*)d_ws + XQ_OFF;
    float*  xs = (float*)((char*)d_ws + XS_OFF);
    int8_t* w8 = (int8_t*)d_ws + W8_OFF;

    prep_kernel<<<T_DIM / 4 + (N_DIM * (K_DIM / 16)) / 256, 256, 0, stream>>>(
        x, xq, xs, w32, w8);
    gemm_i8_kernel<<<(T_DIM / BM) * (N_DIM / BN), 512, 0, stream>>>(
        xq, w8, xs, wsc, bias, out);
}